// Round 5
// baseline (1368.296 us; speedup 1.0000x reference)
//
#include <hip/hip_runtime.h>
#include <stdint.h>

// Problem constants (from reference setup_inputs)
#define N_NODES 50000
#define E_EDGES 400000
#define IN_DIM  128
#define ED_DIM  16
#define K_DIM   144           // IN + ED
#define KT_N    5             // k-tiles of 32 -> K padded to 160
#define P_N     3
#define OUT_DIM 128
#define NCOL    384           // P * OUT
#define NT_N    24            // NCOL / 16
#define ETILE   64            // edges per MFMA tile
#define ASTRIDE 168           // LDS A row stride in bf16 elems

#define DPB     32            // dsts per phase-B block
#define NBLK_B  1563          // ceil(50000/32)
#define NC_PAD  50176         // counts padded to 196*256
#define SB      196           // scan blocks

typedef float  f32x4  __attribute__((ext_vector_type(4)));
typedef __bf16 bf16x8 __attribute__((ext_vector_type(8)));

__device__ __forceinline__ unsigned short f2bf(float f) {
    union { float f; unsigned u; } v; v.f = f;
    unsigned u = v.u + 0x7fffu + ((v.u >> 16) & 1u);   // RTNE
    return (unsigned short)(u >> 16);
}

// ---------------- W repack ----------------
__global__ void pack_w(const float* __restrict__ W, unsigned short* __restrict__ Bpack) {
    int idx = blockIdx.x * blockDim.x + threadIdx.x;
    if (idx >= NT_N * KT_N * 64 * 8) return;
    int j    = idx & 7;
    int lane = (idx >> 3) & 63;
    int kt   = (idx >> 9) % KT_N;
    int nt   = idx / (KT_N * 512);
    int nc   = lane & 15;
    int kr   = ((lane >> 4) << 3) + j;
    int f    = kt * 32 + kr;
    int n    = nt * 16 + nc;
    int p    = n >> 7;
    int o    = n & 127;
    float val = (f < K_DIM) ? W[(p * K_DIM + f) * OUT_DIM + o] : 0.0f;
    Bpack[idx] = f2bf(val);
}

// ---------------- counting sort by dst ----------------
__global__ void k_hist(const int* __restrict__ ei, int* __restrict__ counts) {
    int e = blockIdx.x * 256 + threadIdx.x;
    if (e < E_EDGES) atomicAdd(&counts[ei[E_EDGES + e]], 1);
}

__global__ void k_scan1(const int* __restrict__ counts, int* __restrict__ offsets,
                        int* __restrict__ bsums) {
    __shared__ int tmp[256];
    int t = threadIdx.x;
    int i = blockIdx.x * 256 + t;
    int v = counts[i];
    tmp[t] = v; __syncthreads();
    for (int off = 1; off < 256; off <<= 1) {
        int add = (t >= off) ? tmp[t - off] : 0;
        __syncthreads();
        tmp[t] += add;
        __syncthreads();
    }
    offsets[i] = tmp[t] - v;               // block-local exclusive
    if (t == 255) bsums[blockIdx.x] = tmp[t];
}

__global__ void k_scan2(int* __restrict__ bsums) {
    __shared__ int tmp[256];
    int t = threadIdx.x;
    int v = (t < SB) ? bsums[t] : 0;
    tmp[t] = v; __syncthreads();
    for (int off = 1; off < 256; off <<= 1) {
        int add = (t >= off) ? tmp[t - off] : 0;
        __syncthreads();
        tmp[t] += add;
        __syncthreads();
    }
    if (t < SB) bsums[t] = tmp[t] - v;     // exclusive, in place
}

__global__ void k_scan3(int* __restrict__ offsets, const int* __restrict__ bsums,
                        int* __restrict__ cursor) {
    int i = blockIdx.x * 256 + threadIdx.x;
    int v = offsets[i] + bsums[i >> 8];
    offsets[i] = v;
    cursor[i]  = v;
}

__global__ void k_scatter(const int* __restrict__ ei, const float* __restrict__ etime,
                          int* __restrict__ cursor, int* __restrict__ perm,
                          int* __restrict__ ssrc, int* __restrict__ sdst,
                          float* __restrict__ stime) {
    int e = blockIdx.x * 256 + threadIdx.x;
    if (e >= E_EDGES) return;
    int d = ei[E_EDGES + e];
    int pos = atomicAdd(&cursor[d], 1);
    perm[pos]  = e;
    ssrc[pos]  = ei[e];
    sdst[pos]  = d;
    stime[pos] = etime[e];
}

// ---------------- phase B: dst-owned GEMM + LDS accumulate ----------------
// NOTE: no min-waves-per-EU arg! Round-4's (512,4) capped VGPR+AGPR at 128 and
// forced per-tile scratch spills (~320 MB r+w of mystery HBM traffic). LDS
// (74 KB) already limits occupancy to 2 blocks/CU; let the allocator breathe.
__global__ __launch_bounds__(512) void mpc_phaseB(
    const float* __restrict__ x,
    const float* __restrict__ edge_attr,
    const float* __restrict__ current_time,
    const unsigned short* __restrict__ Bpack,
    const float* __restrict__ bvec,
    const float* __restrict__ decay,
    const int*   __restrict__ offsets,
    const int*   __restrict__ perm,
    const int*   __restrict__ ssrc,
    const int*   __restrict__ sdst,
    const float* __restrict__ stime,
    float* __restrict__ out)
{
    __shared__ __align__(16) unsigned short Alds[ETILE][ASTRIDE];
    __shared__ float accL[DPB + 1][385];       // +1 dump row; stride 385 breaks bank alias
    __shared__ int   src_lds[ETILE];
    __shared__ int   pe_lds[ETILE];
    __shared__ int   dl_lds[ETILE];
    __shared__ float wt_lds[ETILE][P_N];
    __shared__ int   s_bounds[2];

    const int tid = threadIdx.x;
    const int d0  = blockIdx.x * DPB;

    if (tid == 0) { s_bounds[0] = offsets[d0]; s_bounds[1] = offsets[d0 + DPB]; }
    for (int i = tid; i < (DPB + 1) * 385; i += 512) ((float*)accL)[i] = 0.0f;
    __syncthreads();
    const int off0 = s_bounds[0], off1 = s_bounds[1];

    const float4* x4  = (const float4*)x;
    const float4* ea4 = (const float4*)edge_attr;
    const float ct = current_time[0];

    const int w    = tid >> 6;
    const int lane = tid & 63;
    const int row  = lane & 15;
    const int khi  = lane >> 4;

    // tile-invariant epilogue constants (hoisted)
    int   ncol[3], pcol[3];
    float bval[3];
#pragma unroll
    for (int ni = 0; ni < 3; ++ni) {
        ncol[ni] = (w * 3 + ni) * 16 + row;
        pcol[ni] = ncol[ni] >> 7;
        bval[ni] = bvec[ncol[ni]];
    }

    for (int est = off0; est < off1; est += ETILE) {
        // --- meta staging ---
        if (tid < ETILE) {
            int pos = est + tid;
            bool valid = pos < off1;
            src_lds[tid] = valid ? ssrc[pos] : 0;
            pe_lds[tid]  = valid ? perm[pos] : 0;
            dl_lds[tid]  = valid ? (sdst[pos] - d0) : DPB;   // invalid -> dump row
        } else if (tid < 256) {
            int t2 = tid - ETILE;
            if (t2 < ETILE * P_N) {
                int e = t2 / P_N, p = t2 % P_N;
                int pos = est + e;
                float tm = (pos < off1) ? stime[pos] : 0.0f;
                wt_lds[e][p] = __expf(-decay[p] * (ct - tm));
            }
        }
        __syncthreads();

        // --- A staging: [64][160] bf16, 40 uint2-chunks/row (32 x | 4 ea | 4 zero) ---
        for (int i = tid; i < ETILE * 40; i += 512) {
            int e = i / 40, q = i % 40;
            uint2 val;
            if (q < 36) {
                float4 v;
                if (q < 32) v = x4[(size_t)src_lds[e] * 32 + q];
                else        v = ea4[(size_t)pe_lds[e] * 4 + (q - 32)];
                unsigned lo = (unsigned)f2bf(v.x) | ((unsigned)f2bf(v.y) << 16);
                unsigned hi = (unsigned)f2bf(v.z) | ((unsigned)f2bf(v.w) << 16);
                val = make_uint2(lo, hi);
            } else {
                val = make_uint2(0u, 0u);
            }
            *(uint2*)&Alds[e][q * 4] = val;
        }
        __syncthreads();

        // --- MFMA: 64 edges x 384 cols ---
        f32x4 acc[4][3];
#pragma unroll
        for (int mi = 0; mi < 4; ++mi)
#pragma unroll
            for (int ni = 0; ni < 3; ++ni)
                acc[mi][ni] = (f32x4){0.f, 0.f, 0.f, 0.f};

#pragma unroll
        for (int kt = 0; kt < KT_N; ++kt) {
            bf16x8 a[4], bf[3];
#pragma unroll
            for (int mi = 0; mi < 4; ++mi)
                a[mi] = *(const bf16x8*)&Alds[mi * 16 + row][kt * 32 + khi * 8];
#pragma unroll
            for (int ni = 0; ni < 3; ++ni) {
                int nt = w * 3 + ni;
                bf[ni] = *(const bf16x8*)&Bpack[(size_t)(((nt * KT_N) + kt) * 64 + lane) * 8];
            }
#pragma unroll
            for (int mi = 0; mi < 4; ++mi)
#pragma unroll
                for (int ni = 0; ni < 3; ++ni)
                    acc[mi][ni] = __builtin_amdgcn_mfma_f32_16x16x32_bf16(
                        a[mi], bf[ni], acc[mi][ni], 0, 0, 0);
        }

        // --- epilogue: bias + temporal weight, accumulate into LDS (ds_add) ---
#pragma unroll
        for (int ni = 0; ni < 3; ++ni) {
            int n = ncol[ni], p = pcol[ni];
            float bv = bval[ni];
#pragma unroll
            for (int mi = 0; mi < 4; ++mi) {
#pragma unroll
                for (int j = 0; j < 4; ++j) {
                    int e = mi * 16 + khi * 4 + j;
                    float contrib = (acc[mi][ni][j] + bv) * wt_lds[e][p];
                    atomicAdd(&accL[dl_lds[e]][n], contrib);
                }
            }
        }
        __syncthreads();   // ds_adds done before staging overwrite / next iter
    }

    // --- write out: plain coalesced stores, no global atomics ---
    for (int i = tid; i < DPB * NCOL; i += 512) {
        int r = i / NCOL, c = i % NCOL;
        int d = d0 + r;
        if (d < N_NODES) out[(size_t)d * NCOL + c] = accL[r][c];
    }
}

extern "C" void kernel_launch(void* const* d_in, const int* in_sizes, int n_in,
                              void* d_out, int out_size, void* d_ws, size_t ws_size,
                              hipStream_t stream) {
    const float* x            = (const float*)d_in[0];
    const int*   edge_index   = (const int*)d_in[1];
    const float* edge_attr    = (const float*)d_in[2];
    const float* edge_time    = (const float*)d_in[3];
    const float* current_time = (const float*)d_in[4];
    const float* W            = (const float*)d_in[5];
    const float* bvec         = (const float*)d_in[6];
    const float* decay        = (const float*)d_in[7];
    float* out = (float*)d_out;

    // workspace layout (bytes)
    char* ws = (char*)d_ws;
    unsigned short* Bpack = (unsigned short*)(ws);                 // 122880
    int*   counts  = (int*)  (ws + 122880);                        // 200704
    int*   offsets = (int*)  (ws + 323584);                        // 200704
    int*   cursor  = (int*)  (ws + 524288);                        // 200704
    int*   bsums   = (int*)  (ws + 724992);                        // 1024
    int*   perm    = (int*)  (ws + 726016);                        // 1600000
    int*   ssrc    = (int*)  (ws + 2326016);                       // 1600000
    int*   sdst    = (int*)  (ws + 3926016);                       // 1600000
    float* stime   = (float*)(ws + 5526016);                       // 1600000 -> 7.13 MB total

    hipMemsetAsync(counts, 0, (size_t)NC_PAD * 4, stream);

    pack_w<<<(NT_N * KT_N * 64 * 8 + 255) / 256, 256, 0, stream>>>(W, Bpack);

    k_hist   <<<(E_EDGES + 255) / 256, 256, 0, stream>>>(edge_index, counts);
    k_scan1  <<<SB, 256, 0, stream>>>(counts, offsets, bsums);
    k_scan2  <<<1, 256, 0, stream>>>(bsums);
    k_scan3  <<<SB, 256, 0, stream>>>(offsets, bsums, cursor);
    k_scatter<<<(E_EDGES + 255) / 256, 256, 0, stream>>>(edge_index, edge_time, cursor,
                                                         perm, ssrc, sdst, stime);

    mpc_phaseB<<<NBLK_B, 512, 0, stream>>>(x, edge_attr, current_time, Bpack, bvec,
                                           decay, offsets, perm, ssrc, sdst, stime, out);
}

// Round 6
// 509.499 us; speedup vs baseline: 2.6856x; 2.6856x over previous
//
#include <hip/hip_runtime.h>
#include <stdint.h>

// Problem constants (from reference setup_inputs)
#define N_NODES 50000
#define E_EDGES 400000
#define IN_DIM  128
#define ED_DIM  16
#define K_DIM   144           // IN + ED
#define KT_N    5             // k-tiles of 32 -> K padded to 160
#define P_N     3
#define OUT_DIM 128
#define NCOL    384           // P * OUT
#define NT_N    24            // NCOL / 16
#define ETILE   64            // edges per MFMA tile -> E = 6250 * 64 exactly
#define NBLK    6250
#define ASTRIDE 168           // LDS A row stride in bf16 elems

#define NC_PAD  50176         // counts padded to 196*256
#define SB      196           // scan blocks

typedef float  f32x4  __attribute__((ext_vector_type(4)));
typedef __bf16 bf16x8 __attribute__((ext_vector_type(8)));

__device__ __forceinline__ unsigned short f2bf(float f) {
    union { float f; unsigned u; } v; v.f = f;
    unsigned u = v.u + 0x7fffu + ((v.u >> 16) & 1u);   // RTNE
    return (unsigned short)(u >> 16);
}

// ---------------- W repack ----------------
__global__ void pack_w(const float* __restrict__ W, unsigned short* __restrict__ Bpack) {
    int idx = blockIdx.x * blockDim.x + threadIdx.x;
    if (idx >= NT_N * KT_N * 64 * 8) return;
    int j    = idx & 7;
    int lane = (idx >> 3) & 63;
    int kt   = (idx >> 9) % KT_N;
    int nt   = idx / (KT_N * 512);
    int nc   = lane & 15;
    int kr   = ((lane >> 4) << 3) + j;
    int f    = kt * 32 + kr;
    int n    = nt * 16 + nc;
    int p    = n >> 7;
    int o    = n & 127;
    float val = (f < K_DIM) ? W[(p * K_DIM + f) * OUT_DIM + o] : 0.0f;
    Bpack[idx] = f2bf(val);
}

// ---------------- counting sort by dst ----------------
__global__ void k_hist(const int* __restrict__ ei, int* __restrict__ counts) {
    int e = blockIdx.x * 256 + threadIdx.x;
    if (e < E_EDGES) atomicAdd(&counts[ei[E_EDGES + e]], 1);
}

__global__ void k_scan1(const int* __restrict__ counts, int* __restrict__ offsets,
                        int* __restrict__ bsums) {
    __shared__ int tmp[256];
    int t = threadIdx.x;
    int i = blockIdx.x * 256 + t;
    int v = counts[i];
    tmp[t] = v; __syncthreads();
    for (int off = 1; off < 256; off <<= 1) {
        int add = (t >= off) ? tmp[t - off] : 0;
        __syncthreads();
        tmp[t] += add;
        __syncthreads();
    }
    offsets[i] = tmp[t] - v;               // block-local exclusive
    if (t == 255) bsums[blockIdx.x] = tmp[t];
}

__global__ void k_scan2(int* __restrict__ bsums) {
    __shared__ int tmp[256];
    int t = threadIdx.x;
    int v = (t < SB) ? bsums[t] : 0;
    tmp[t] = v; __syncthreads();
    for (int off = 1; off < 256; off <<= 1) {
        int add = (t >= off) ? tmp[t - off] : 0;
        __syncthreads();
        tmp[t] += add;
        __syncthreads();
    }
    if (t < SB) bsums[t] = tmp[t] - v;     // exclusive, in place
}

__global__ void k_scan3(int* __restrict__ offsets, const int* __restrict__ bsums,
                        int* __restrict__ cursor) {
    int i = blockIdx.x * 256 + threadIdx.x;
    int v = offsets[i] + bsums[i >> 8];
    offsets[i] = v;
    cursor[i]  = v;
}

// pack each sorted edge as int4 {src, orig_e, dst, time_bits} -> one 16B store
__global__ void k_scatter(const int* __restrict__ ei, const float* __restrict__ etime,
                          int* __restrict__ cursor, int4* __restrict__ equad) {
    int e = blockIdx.x * 256 + threadIdx.x;
    if (e >= E_EDGES) return;
    int d = ei[E_EDGES + e];
    int pos = atomicAdd(&cursor[d], 1);
    int4 q;
    q.x = ei[e];
    q.y = e;
    q.z = d;
    q.w = __float_as_int(etime[e]);
    equad[pos] = q;
}

// ---------------- phase B: sorted-stream GEMM + in-register run-collapse ----
// Round-2 structure (1 tile/block, 23KB LDS, full occupancy, global atomics)
// but edges arrive dst-sorted, so each lane's 4 consecutive accumulator rows
// collapse equal-dst runs in-register first: ~153.6M -> ~53M global atomics.
// NOTE: __launch_bounds__ has NO min-waves arg (round-4 lesson: (512,4) capped
// unified VGPR+AGPR at 128 and forced scratch spills).
__global__ __launch_bounds__(512) void mpc_phaseB(
    const float* __restrict__ x,
    const float* __restrict__ edge_attr,
    const float* __restrict__ current_time,
    const unsigned short* __restrict__ Bpack,
    const float* __restrict__ bvec,
    const float* __restrict__ decay,
    const int4*  __restrict__ equad,
    float* __restrict__ out)
{
    __shared__ __align__(16) unsigned short Alds[ETILE][ASTRIDE];
    __shared__ int   src_lds[ETILE];
    __shared__ int   pe_lds[ETILE];
    __shared__ int   dst_lds[ETILE];
    __shared__ float wt_lds[ETILE][P_N];

    const int tid = threadIdx.x;
    const int e0  = blockIdx.x * ETILE;
    const float ct = current_time[0];

    // --- meta staging: one coalesced int4 per edge ---
    if (tid < ETILE) {
        int4 q = equad[e0 + tid];
        src_lds[tid] = q.x;
        pe_lds[tid]  = q.y;
        dst_lds[tid] = q.z;
        float dtv = ct - __int_as_float(q.w);
        wt_lds[tid][0] = __expf(-decay[0] * dtv);
        wt_lds[tid][1] = __expf(-decay[1] * dtv);
        wt_lds[tid][2] = __expf(-decay[2] * dtv);
    }
    __syncthreads();

    // --- A staging: [64][160] bf16, 40 uint2-chunks/row (32 x | 4 ea | 4 zero) ---
    const float4* x4  = (const float4*)x;
    const float4* ea4 = (const float4*)edge_attr;
    for (int i = tid; i < ETILE * 40; i += 512) {
        int e = i / 40, q = i % 40;
        uint2 val;
        if (q < 36) {
            float4 v;
            if (q < 32) v = x4[(size_t)src_lds[e] * 32 + q];
            else        v = ea4[(size_t)pe_lds[e] * 4 + (q - 32)];
            unsigned lo = (unsigned)f2bf(v.x) | ((unsigned)f2bf(v.y) << 16);
            unsigned hi = (unsigned)f2bf(v.z) | ((unsigned)f2bf(v.w) << 16);
            val = make_uint2(lo, hi);
        } else {
            val = make_uint2(0u, 0u);
        }
        *(uint2*)&Alds[e][q * 4] = val;
    }
    __syncthreads();

    const int w    = tid >> 6;
    const int lane = tid & 63;
    const int row  = lane & 15;
    const int khi  = lane >> 4;

    f32x4 acc[4][3];
#pragma unroll
    for (int mi = 0; mi < 4; ++mi)
#pragma unroll
        for (int ni = 0; ni < 3; ++ni)
            acc[mi][ni] = (f32x4){0.f, 0.f, 0.f, 0.f};

#pragma unroll
    for (int kt = 0; kt < KT_N; ++kt) {
        bf16x8 a[4], bf[3];
#pragma unroll
        for (int mi = 0; mi < 4; ++mi)
            a[mi] = *(const bf16x8*)&Alds[mi * 16 + row][kt * 32 + khi * 8];
#pragma unroll
        for (int ni = 0; ni < 3; ++ni) {
            int nt = w * 3 + ni;
            bf[ni] = *(const bf16x8*)&Bpack[(size_t)(((nt * KT_N) + kt) * 64 + lane) * 8];
        }
#pragma unroll
        for (int mi = 0; mi < 4; ++mi)
#pragma unroll
            for (int ni = 0; ni < 3; ++ni)
                acc[mi][ni] = __builtin_amdgcn_mfma_f32_16x16x32_bf16(
                    a[mi], bf[ni], acc[mi][ni], 0, 0, 0);
    }

    // --- epilogue: bias + temporal weight, collapse equal-dst runs, atomic ---
    int   ncol[3], pcol[3];
    float bval[3];
#pragma unroll
    for (int ni = 0; ni < 3; ++ni) {
        ncol[ni] = (w * 3 + ni) * 16 + row;
        pcol[ni] = ncol[ni] >> 7;
        bval[ni] = bvec[ncol[ni]];
    }

#pragma unroll
    for (int mi = 0; mi < 4; ++mi) {
        const int eb = mi * 16 + khi * 4;
        const int dd0 = dst_lds[eb + 0];
        const int dd1 = dst_lds[eb + 1];
        const int dd2 = dst_lds[eb + 2];
        const int dd3 = dst_lds[eb + 3];
#pragma unroll
        for (int ni = 0; ni < 3; ++ni) {
            const int n = ncol[ni], p = pcol[ni];
            const float bv = bval[ni];
            float c0 = (acc[mi][ni][0] + bv) * wt_lds[eb + 0][p];
            float c1 = (acc[mi][ni][1] + bv) * wt_lds[eb + 1][p];
            float c2 = (acc[mi][ni][2] + bv) * wt_lds[eb + 2][p];
            float c3 = (acc[mi][ni][3] + bv) * wt_lds[eb + 3][p];
            float run = c0; int rd = dd0;
            if (dd1 == rd) run += c1;
            else { atomicAdd(&out[(size_t)rd * NCOL + n], run); run = c1; rd = dd1; }
            if (dd2 == rd) run += c2;
            else { atomicAdd(&out[(size_t)rd * NCOL + n], run); run = c2; rd = dd2; }
            if (dd3 == rd) run += c3;
            else { atomicAdd(&out[(size_t)rd * NCOL + n], run); run = c3; rd = dd3; }
            atomicAdd(&out[(size_t)rd * NCOL + n], run);
        }
    }
}

extern "C" void kernel_launch(void* const* d_in, const int* in_sizes, int n_in,
                              void* d_out, int out_size, void* d_ws, size_t ws_size,
                              hipStream_t stream) {
    const float* x            = (const float*)d_in[0];
    const int*   edge_index   = (const int*)d_in[1];
    const float* edge_attr    = (const float*)d_in[2];
    const float* edge_time    = (const float*)d_in[3];
    const float* current_time = (const float*)d_in[4];
    const float* W            = (const float*)d_in[5];
    const float* bvec         = (const float*)d_in[6];
    const float* decay        = (const float*)d_in[7];
    float* out = (float*)d_out;

    // workspace layout (bytes)
    char* ws = (char*)d_ws;
    unsigned short* Bpack = (unsigned short*)(ws);                 // 122880
    int*   counts  = (int*)  (ws + 122880);                        // 200704
    int*   offsets = (int*)  (ws + 323584);                        // 200704
    int*   cursor  = (int*)  (ws + 524288);                        // 200704
    int*   bsums   = (int*)  (ws + 724992);                        // 1024
    int4*  equad   = (int4*) (ws + 726016);                        // 6.4 MB -> 7.13 MB total

    hipMemsetAsync(counts, 0, (size_t)NC_PAD * 4, stream);
    hipMemsetAsync(d_out, 0, (size_t)out_size * sizeof(float), stream);

    pack_w<<<(NT_N * KT_N * 64 * 8 + 255) / 256, 256, 0, stream>>>(W, Bpack);

    k_hist   <<<(E_EDGES + 255) / 256, 256, 0, stream>>>(edge_index, counts);
    k_scan1  <<<SB, 256, 0, stream>>>(counts, offsets, bsums);
    k_scan2  <<<1, 256, 0, stream>>>(bsums);
    k_scan3  <<<SB, 256, 0, stream>>>(offsets, bsums, cursor);
    k_scatter<<<(E_EDGES + 255) / 256, 256, 0, stream>>>(edge_index, edge_time, cursor, equad);

    mpc_phaseB<<<NBLK, 512, 0, stream>>>(x, edge_attr, current_time, Bpack, bvec,
                                         decay, equad, out);
}

// Round 7
// 332.405 us; speedup vs baseline: 4.1163x; 1.5328x over previous
//
#include <hip/hip_runtime.h>
#include <stdint.h>

// Problem constants (from reference setup_inputs)
#define N_NODES 50000
#define E_EDGES 400000
#define IN_DIM  128
#define ED_DIM  16
#define K_DIM   144           // IN + ED
#define KT_N    5             // k-tiles of 32 -> K padded to 160
#define P_N     3
#define OUT_DIM 128
#define NCOL    384           // P * OUT
#define NT_N    24            // NCOL / 16
#define ETILE   64            // edges per MFMA tile -> E = 6250 * 64 exactly
#define NBLK    6250
#define ASTRIDE 168           // LDS A row stride in bf16 elems

#define NC_PAD  50176         // counts padded to 196*256
#define SB      196           // scan blocks

typedef float  f32x4  __attribute__((ext_vector_type(4)));
typedef __bf16 bf16x8 __attribute__((ext_vector_type(8)));

__device__ __forceinline__ unsigned short f2bf(float f) {
    union { float f; unsigned u; } v; v.f = f;
    unsigned u = v.u + 0x7fffu + ((v.u >> 16) & 1u);   // RTNE
    return (unsigned short)(u >> 16);
}

// ---------------- W repack ----------------
__global__ void pack_w(const float* __restrict__ W, unsigned short* __restrict__ Bpack) {
    int idx = blockIdx.x * blockDim.x + threadIdx.x;
    if (idx >= NT_N * KT_N * 64 * 8) return;
    int j    = idx & 7;
    int lane = (idx >> 3) & 63;
    int kt   = (idx >> 9) % KT_N;
    int nt   = idx / (KT_N * 512);
    int nc   = lane & 15;
    int kr   = ((lane >> 4) << 3) + j;
    int f    = kt * 32 + kr;
    int n    = nt * 16 + nc;
    int p    = n >> 7;
    int o    = n & 127;
    float val = (f < K_DIM) ? W[(p * K_DIM + f) * OUT_DIM + o] : 0.0f;
    Bpack[idx] = f2bf(val);
}

// ---------------- counting sort by dst ----------------
__global__ void k_hist(const int* __restrict__ ei, int* __restrict__ counts) {
    int e = blockIdx.x * 256 + threadIdx.x;
    if (e < E_EDGES) atomicAdd(&counts[ei[E_EDGES + e]], 1);
}

__global__ void k_scan1(const int* __restrict__ counts, int* __restrict__ offsets,
                        int* __restrict__ bsums) {
    __shared__ int tmp[256];
    int t = threadIdx.x;
    int i = blockIdx.x * 256 + t;
    int v = counts[i];
    tmp[t] = v; __syncthreads();
    for (int off = 1; off < 256; off <<= 1) {
        int add = (t >= off) ? tmp[t - off] : 0;
        __syncthreads();
        tmp[t] += add;
        __syncthreads();
    }
    offsets[i] = tmp[t] - v;               // block-local exclusive
    if (t == 255) bsums[blockIdx.x] = tmp[t];
}

__global__ void k_scan2(int* __restrict__ bsums) {
    __shared__ int tmp[256];
    int t = threadIdx.x;
    int v = (t < SB) ? bsums[t] : 0;
    tmp[t] = v; __syncthreads();
    for (int off = 1; off < 256; off <<= 1) {
        int add = (t >= off) ? tmp[t - off] : 0;
        __syncthreads();
        tmp[t] += add;
        __syncthreads();
    }
    if (t < SB) bsums[t] = tmp[t] - v;     // exclusive, in place
}

__global__ void k_scan3(int* __restrict__ offsets, const int* __restrict__ bsums,
                        int* __restrict__ cursor) {
    int i = blockIdx.x * 256 + threadIdx.x;
    int v = offsets[i] + bsums[i >> 8];
    offsets[i] = v;
    cursor[i]  = v;
}

// pack each sorted edge as int4 {src, orig_e, dst, time_bits} -> one 16B store
__global__ void k_scatter(const int* __restrict__ ei, const float* __restrict__ etime,
                          int* __restrict__ cursor, int4* __restrict__ equad) {
    int e = blockIdx.x * 256 + threadIdx.x;
    if (e >= E_EDGES) return;
    int d = ei[E_EDGES + e];
    int pos = atomicAdd(&cursor[d], 1);
    int4 q;
    q.x = ei[e];
    q.y = e;
    q.z = d;
    q.w = __float_as_int(etime[e]);
    equad[pos] = q;
}

// ---------------- phase B: sorted-stream GEMM + contiguous-span collapse ----
// KEY CHANGE vs round 6: sorted edge s = khi*16 + mi*4 + j is staged into MFMA
// row r = mi*16 + khi*4 + j (swap the two 2-bit fields). The D-fragment layout
// (row = mi*16 + khi*4 + j per thread) then hands each thread 16 CONTIGUOUS
// sorted edges, so dst-runs (avg length 8) collapse fully in-register:
// ~65.8M -> ~29M atomics, and no intra-instruction same-address conflicts.
// NOTE: __launch_bounds__ has NO min-waves arg (round-4 lesson: (512,4) capped
// unified VGPR+AGPR at 128 and forced scratch spills).
__global__ __launch_bounds__(512) void mpc_phaseB(
    const float* __restrict__ x,
    const float* __restrict__ edge_attr,
    const float* __restrict__ current_time,
    const unsigned short* __restrict__ Bpack,
    const float* __restrict__ bvec,
    const float* __restrict__ decay,
    const int4*  __restrict__ equad,
    float* __restrict__ out)
{
    __shared__ __align__(16) unsigned short Alds[ETILE][ASTRIDE];
    __shared__ int   src_lds[ETILE];     // indexed by SORTED pos s
    __shared__ int   pe_lds[ETILE];      // indexed by SORTED pos s
    __shared__ int   dst_lds[ETILE];     // indexed by SORTED pos s
    __shared__ float wt_lds[ETILE][P_N]; // indexed by SORTED pos s

    const int tid = threadIdx.x;
    const int e0  = blockIdx.x * ETILE;
    const float ct = current_time[0];

    // --- meta staging: one coalesced int4 per sorted edge ---
    if (tid < ETILE) {
        int4 q = equad[e0 + tid];
        src_lds[tid] = q.x;
        pe_lds[tid]  = q.y;
        dst_lds[tid] = q.z;
        float dtv = ct - __int_as_float(q.w);
        wt_lds[tid][0] = __expf(-decay[0] * dtv);
        wt_lds[tid][1] = __expf(-decay[1] * dtv);
        wt_lds[tid][2] = __expf(-decay[2] * dtv);
    }
    __syncthreads();

    // --- A staging: MFMA row r holds sorted edge s(r) (field swap) ---
    // r = (hi<<4)|(md<<2)|j  ->  s = (md<<4)|(hi<<2)|j
    const float4* x4  = (const float4*)x;
    const float4* ea4 = (const float4*)edge_attr;
    for (int i = tid; i < ETILE * 40; i += 512) {
        int e = i / 40, q = i % 40;
        int se = (((e >> 2) & 3) << 4) | (((e >> 4) & 3) << 2) | (e & 3);
        uint2 val;
        if (q < 36) {
            float4 v;
            if (q < 32) v = x4[(size_t)src_lds[se] * 32 + q];
            else        v = ea4[(size_t)pe_lds[se] * 4 + (q - 32)];
            unsigned lo = (unsigned)f2bf(v.x) | ((unsigned)f2bf(v.y) << 16);
            unsigned hi = (unsigned)f2bf(v.z) | ((unsigned)f2bf(v.w) << 16);
            val = make_uint2(lo, hi);
        } else {
            val = make_uint2(0u, 0u);
        }
        *(uint2*)&Alds[e][q * 4] = val;
    }
    __syncthreads();

    const int w    = tid >> 6;
    const int lane = tid & 63;
    const int row  = lane & 15;
    const int khi  = lane >> 4;

    f32x4 acc[4][3];
#pragma unroll
    for (int mi = 0; mi < 4; ++mi)
#pragma unroll
        for (int ni = 0; ni < 3; ++ni)
            acc[mi][ni] = (f32x4){0.f, 0.f, 0.f, 0.f};

#pragma unroll
    for (int kt = 0; kt < KT_N; ++kt) {
        bf16x8 a[4], bf[3];
#pragma unroll
        for (int mi = 0; mi < 4; ++mi)
            a[mi] = *(const bf16x8*)&Alds[mi * 16 + row][kt * 32 + khi * 8];
#pragma unroll
        for (int ni = 0; ni < 3; ++ni) {
            int nt = w * 3 + ni;
            bf[ni] = *(const bf16x8*)&Bpack[(size_t)(((nt * KT_N) + kt) * 64 + lane) * 8];
        }
#pragma unroll
        for (int mi = 0; mi < 4; ++mi)
#pragma unroll
            for (int ni = 0; ni < 3; ++ni)
                acc[mi][ni] = __builtin_amdgcn_mfma_f32_16x16x32_bf16(
                    a[mi], bf[ni], acc[mi][ni], 0, 0, 0);
    }

    // --- epilogue: thread's acc (mi,j) = sorted edges [khi*16, khi*16+16) ---
    // acc value for sorted edge s = khi*16 + t is acc[t>>2][ni][t&3].
    int   ncol[3], pcol[3];
    float bval[3];
#pragma unroll
    for (int ni = 0; ni < 3; ++ni) {
        ncol[ni] = (w * 3 + ni) * 16 + row;
        pcol[ni] = ncol[ni] >> 7;
        bval[ni] = bvec[ncol[ni]];
    }

    const int sbase = khi * 16;
    int dsp[16];
#pragma unroll
    for (int t = 0; t < 16; ++t) dsp[t] = dst_lds[sbase + t];

#pragma unroll
    for (int ni = 0; ni < 3; ++ni) {
        const int n = ncol[ni], p = pcol[ni];
        const float bv = bval[ni];
        float run = 0.0f;
        int   rd  = dsp[0];
#pragma unroll
        for (int t = 0; t < 16; ++t) {
            float c = (acc[t >> 2][ni][t & 3] + bv) * wt_lds[sbase + t][p];
            int d = dsp[t];
            if (d != rd) {
                atomicAdd(&out[(size_t)rd * NCOL + n], run);
                run = 0.0f;
                rd  = d;
            }
            run += c;
        }
        atomicAdd(&out[(size_t)rd * NCOL + n], run);
    }
}

extern "C" void kernel_launch(void* const* d_in, const int* in_sizes, int n_in,
                              void* d_out, int out_size, void* d_ws, size_t ws_size,
                              hipStream_t stream) {
    const float* x            = (const float*)d_in[0];
    const int*   edge_index   = (const int*)d_in[1];
    const float* edge_attr    = (const float*)d_in[2];
    const float* edge_time    = (const float*)d_in[3];
    const float* current_time = (const float*)d_in[4];
    const float* W            = (const float*)d_in[5];
    const float* bvec         = (const float*)d_in[6];
    const float* decay        = (const float*)d_in[7];
    float* out = (float*)d_out;

    // workspace layout (bytes)
    char* ws = (char*)d_ws;
    unsigned short* Bpack = (unsigned short*)(ws);                 // 122880
    int*   counts  = (int*)  (ws + 122880);                        // 200704
    int*   offsets = (int*)  (ws + 323584);                        // 200704
    int*   cursor  = (int*)  (ws + 524288);                        // 200704
    int*   bsums   = (int*)  (ws + 724992);                        // 1024
    int4*  equad   = (int4*) (ws + 726016);                        // 6.4 MB -> 7.13 MB total

    hipMemsetAsync(counts, 0, (size_t)NC_PAD * 4, stream);
    hipMemsetAsync(d_out, 0, (size_t)out_size * sizeof(float), stream);

    pack_w<<<(NT_N * KT_N * 64 * 8 + 255) / 256, 256, 0, stream>>>(W, Bpack);

    k_hist   <<<(E_EDGES + 255) / 256, 256, 0, stream>>>(edge_index, counts);
    k_scan1  <<<SB, 256, 0, stream>>>(counts, offsets, bsums);
    k_scan2  <<<1, 256, 0, stream>>>(bsums);
    k_scan3  <<<SB, 256, 0, stream>>>(offsets, bsums, cursor);
    k_scatter<<<(E_EDGES + 255) / 256, 256, 0, stream>>>(edge_index, edge_time, cursor, equad);

    mpc_phaseB<<<NBLK, 512, 0, stream>>>(x, edge_attr, current_time, Bpack, bvec,
                                         decay, equad, out);
}